// Round 12
// baseline (536.152 us; speedup 1.0000x reference)
//
#include <hip/hip_runtime.h>
#include <hip/hip_bf16.h>

typedef unsigned short u16;
typedef unsigned int u32;
typedef __attribute__((ext_vector_type(8))) __bf16 bf16x8;
typedef __attribute__((ext_vector_type(4))) float f32x4;

#define NT 50000
#define NEDGE 1600000
#define GRID 512
#define NWV 8
#define TOTW 4096           // waves; each owns an edge-balanced bucket range
#define NBIN 50176          // padded bins (49*1024)

__device__ __forceinline__ u16 f2bf(float f) {
  unsigned x = __float_as_uint(f);
  x += 0x7fffu + ((x >> 16) & 1u);
  return (u16)(x >> 16);
}

// element index into a [R][128] bf16 tile, 16B-chunk XOR swizzle
__device__ __forceinline__ int swz(int row, int col) {
  return (row << 7) + (col ^ ((row & 7) << 3));
}

// tanh-form GELU via exp2 (gelu(0)==0 exactly — masking relies on this)
__device__ __forceinline__ float gelu(float v) {
  float u = v * v;
  float arg = v * __builtin_fmaf(-0.1029434f, u, -2.3022082f);  // -2*log2e*(c1+c2*u)
  float e = __builtin_amdgcn_exp2f(arg);
  return v * __builtin_amdgcn_rcpf(1.0f + e);
}

__device__ __forceinline__ void atomAddF32(float* p, float v) {
#if defined(__has_builtin)
#if __has_builtin(__builtin_amdgcn_global_atomic_fadd_f32)
  __builtin_amdgcn_global_atomic_fadd_f32((__attribute__((address_space(1))) float*)p, v);
  return;
#endif
#endif
  atomicAdd(p, v);
}

// ---------------- merged prep (cnt zeroed by hipMemsetAsync) ----------------

__global__ void prep_all(const float* __restrict__ H, u16* __restrict__ Hb,
                         const float* __restrict__ W1, const float* __restrict__ W2,
                         u16* __restrict__ wsw, const float* __restrict__ b1,
                         u16* __restrict__ wx) {
  int bid = blockIdx.x, tid = threadIdx.x;
  if (bid < 3125) {                    // H f32 -> bf16, 8 elems/thread
    int t = bid * 256 + tid;
    const float4* s = (const float4*)H + (long)t * 2;
    float4 a = s[0], c = s[1];
    int4 pk;
    pk.x = f2bf(a.x) | ((int)f2bf(a.y) << 16);
    pk.y = f2bf(a.z) | ((int)f2bf(a.w) << 16);
    pk.z = f2bf(c.x) | ((int)f2bf(c.y) << 16);
    pk.w = f2bf(c.z) | ((int)f2bf(c.w) << 16);
    ((int4*)Hb)[t] = pk;
  } else if (bid < 3253) {             // W1^T / W2^T bf16, pre-swizzled
    int t = (bid - 3125) * 256 + tid;  // 0..32767
    int m = t >> 14;
    int p = t & 16383;
    int row = p >> 7;
    int colq = p & 127;
    int k = colq ^ ((row & 7) << 3);
    const float* W = m ? W2 : W1;
    wsw[t] = f2bf(W[k * 128 + row]);
  } else if (bid < 3257) {             // K-ext rows: [W1[128..130][n], b1[n], 0,0,0,0]
    int t = (bid - 3253) * 256 + tid;  // 0..1023
    int row = t >> 3, j = t & 7;
    float v = 0.f;
    if (j < 3) v = W1[(128 + j) * 128 + row];
    else if (j == 3) v = b1[row];
    wx[t] = f2bf(v);
  } else {                             // zero row NT of Hb (mask target)
    if (tid < 16) ((int4*)(Hb + (long)NT * 128))[tid] = make_int4(0, 0, 0, 0);
  }
}

__global__ void copy_h(const float4* __restrict__ H, float4* __restrict__ out) {
  int t = blockIdx.x * 256 + threadIdx.x;
  out[t] = H[t];
}

// ---------------- dst bucket sort (bucket == dst row) ----------------

__global__ void hist_g(const int* __restrict__ ei, u32* __restrict__ cnt) {
  int e = blockIdx.x * 256 + threadIdx.x;   // 6250 blocks
  atomicAdd(&cnt[ei[NEDGE + e]], 1u);
}

__global__ void scan_blk(u32* __restrict__ cnt, u32* __restrict__ btot) {  // <<<49,1024>>>
  __shared__ u32 ls[1024];
  int tid = threadIdx.x;
  int bin = blockIdx.x * 1024 + tid;
  u32 c = cnt[bin];
  ls[tid] = c;
  __syncthreads();
  for (int o = 1; o < 1024; o <<= 1) {
    u32 t = (tid >= o) ? ls[tid - o] : 0u;
    __syncthreads();
    ls[tid] += t;
    __syncthreads();
  }
  cnt[bin] = ls[tid] - c;          // block-local exclusive
  if (tid == 1023) btot[blockIdx.x] = ls[1023];
}

// fin_base with fused btot prefix scan (49 entries, per-block in LDS)
__global__ void fin_base(const u32* __restrict__ cnt, const u32* __restrict__ btot,
                         u32* __restrict__ base, u32* __restrict__ pos) {
  __shared__ u32 bpre[49];
  int tid = threadIdx.x;
  if (tid == 0) {
    u32 run = 0;
    for (int i = 0; i < 49; ++i) { u32 t = btot[i]; bpre[i] = run; run += t; }
  }
  __syncthreads();
  int bin = blockIdx.x * 256 + tid;   // 196*256 = 50176
  if (bin < NT) {
    u32 v = cnt[bin] + bpre[bin >> 10];
    base[bin] = v;
    pos[bin] = v;
  }
  if (bin == NT) base[NT] = NEDGE;
}

// 8B records: {src | ea0bf<<16, ea1bf | ea2bf<<16}
__global__ void scatter_g(const int* __restrict__ ei, const float* __restrict__ ea,
                          u32* __restrict__ pos, uint2* __restrict__ rec) {
  int e = blockIdx.x * 256 + threadIdx.x;   // 6250 blocks
  int d = ei[NEDGE + e];
  int s = ei[e];
  float e0 = ea[e * 3 + 0], e1 = ea[e * 3 + 1], e2 = ea[e * 3 + 2];
  u32 p = atomicAdd(&pos[d], 1u);
  rec[p] = make_uint2((u32)s | ((u32)f2bf(e0) << 16),
                      (u32)f2bf(e1) | ((u32)f2bf(e2) << 16));
}

// ---------------- aggregated message kernel (r8 structure, edge-balanced) ----------------
// D[e][n]: mfma(Hj-rows, W1t-rows); e in (l4,r), n in l15.
// Wave owns buckets whose start offset falls in [gid*E/TOTW, (gid+1)*E/TOTW).

__launch_bounds__(512, 2)
__global__ void msg_agg(const u16* __restrict__ Hb,
                        const u16* __restrict__ wsw,
                        const u16* __restrict__ wx,
                        const u32* __restrict__ base,
                        const uint2* __restrict__ rec,
                        u16* __restrict__ hsb) {
  __shared__ __align__(16) u16 lw1[16384];        // 32 KB, swizzled W1^T
  __shared__ __align__(16) u16 lw1x[128 * 8];     //  2 KB, K-ext rows

  const int tid = threadIdx.x;
  {
    const int4* g = (const int4*)wsw;
    int4* d1 = (int4*)lw1;
#pragma unroll
    for (int i = 0; i < 4; ++i) { int c = tid + i * 512; d1[c] = g[c]; }
  }
  if (tid < 128) ((int4*)lw1x)[tid] = ((const int4*)wx)[tid];
  __syncthreads();   // only barrier

  const int wv = tid >> 6, lane = tid & 63;
  const int l15 = lane & 15, l4 = lane >> 4;
  const int gid = blockIdx.x * NWV + wv;

  // edge-balanced bucket range via binary search on base[]
  const long t0 = ((long)gid * NEDGE) / TOTW;
  const long t1 = ((long)(gid + 1) * NEDGE) / TOTW;
  int lo = 0, hi = NT;
  while (lo < hi) { int mid = (lo + hi) >> 1; if ((long)base[mid] < t0) lo = mid + 1; else hi = mid; }
  const int d0 = lo;
  hi = NT;
  while (lo < hi) { int mid = (lo + hi) >> 1; if ((long)base[mid] < t1) lo = mid + 1; else hi = mid; }
  const int d1i = lo;

  for (int b = d0; b < d1i; ++b) {
    const int start = (int)base[b];
    const int cnt = (int)base[b + 1] - start;

    float racc[8][4];
#pragma unroll
    for (int nt = 0; nt < 8; ++nt)
#pragma unroll
      for (int r = 0; r < 4; ++r) racc[nt][r] = 0.f;

    const int ntile = (cnt + 15) >> 4;
    uint2 r2c = make_uint2(0, 0);
    if (ntile > 0) {
      int i0 = (l15 < cnt) ? l15 : cnt - 1;
      r2c = rec[start + i0];
    }

    for (int t = 0; t < ntile; ++t) {
      // prefetch next tile's rec
      int inx = (t + 1) * 16 + l15;
      if (inx >= cnt) inx = cnt - 1;
      uint2 r2n = rec[start + inx];

      const bool valid = (t * 16 + l15) < cnt;
      // invalid edge -> zero row of Hb and zero K-ext => column contributes exactly 0
      int src = valid ? (int)(r2c.x & 0xFFFFu) : NT;
      u32 x0 = 0u, x1 = 0u;
      if (l4 == 0 && valid) {
        x0 = (r2c.x >> 16) | (r2c.y << 16);       // ea0 | ea1
        x1 = (r2c.y >> 16) | 0x3F800000u;         // ea2 | bf16(1.0)
      }
      int4 xbi = make_int4((int)x0, (int)x1, 0, 0);
      bf16x8 bfrx = *(bf16x8*)&xbi;

      bf16x8 bfc[4];
      {
        const u16* hr = Hb + (long)src * 128;
#pragma unroll
        for (int ks = 0; ks < 4; ++ks)
          bfc[ks] = *(const bf16x8*)(hr + ks * 32 + l4 * 8);
      }

#pragma unroll
      for (int nt = 0; nt < 8; ++nt) {
        bf16x8 afrx = *(const bf16x8*)&lw1x[(nt * 16 + l15) * 8];
        f32x4 acc = (f32x4){0.f, 0.f, 0.f, 0.f};
#pragma unroll
        for (int ks = 0; ks < 4; ++ks) {
          bf16x8 afr = *(const bf16x8*)&lw1[swz(nt * 16 + l15, ks * 32 + l4 * 8)];
          acc = __builtin_amdgcn_mfma_f32_16x16x32_bf16(bfc[ks], afr, acc, 0, 0, 0);
        }
        acc = __builtin_amdgcn_mfma_f32_16x16x32_bf16(bfrx, afrx, acc, 0, 0, 0);
#pragma unroll
        for (int r = 0; r < 4; ++r)
          racc[nt][r] += gelu(acc[r]);            // invalid cols are exactly 0
      }
      r2c = r2n;
    }

    // reduce over e: r in-register, l4 via 2 shfl_xor
    float sv[8];
#pragma unroll
    for (int nt = 0; nt < 8; ++nt) {
      float s = racc[nt][0] + racc[nt][1] + racc[nt][2] + racc[nt][3];
      s += __shfl_xor(s, 16);
      s += __shfl_xor(s, 32);
      sv[nt] = s;
    }
    float sa = (l4 == 0) ? sv[0] : (l4 == 1) ? sv[1] : (l4 == 2) ? sv[2] : sv[3];
    float sb = (l4 == 0) ? sv[4] : (l4 == 1) ? sv[5] : (l4 == 2) ? sv[6] : sv[7];
    u16* hrow = hsb + (long)b * 128;
    hrow[l4 * 16 + l15] = f2bf(sa);               // coalesced 128B store
    hrow[64 + l4 * 16 + l15] = f2bf(sb);          // coalesced 128B store
  }
}

// ---------------- fused layer-2 GEMM + residual + LayerNorm ----------------

__launch_bounds__(256)
__global__ void gemm_ln(const u16* __restrict__ hsb,
                        const float* __restrict__ H,
                        const float* __restrict__ b2,
                        const u16* __restrict__ wsw,
                        const u32* __restrict__ base,
                        const float* __restrict__ gamma,
                        const float* __restrict__ beta,
                        float* __restrict__ out) {
  __shared__ __align__(16) u16 lw2[16384];   // swizzled W2^T
  const int tid = threadIdx.x;
  {
    const int4* g = (const int4*)wsw + 2048;   // W2 half
    int4* d2 = (int4*)lw2;
#pragma unroll
    for (int i = 0; i < 8; ++i) { int c = tid + i * 256; d2[c] = g[c]; }
  }
  __syncthreads();

  const int wv = tid >> 6, lane = tid & 63;
  const int l15 = lane & 15, l4 = lane >> 4;
  const int r0 = (blockIdx.x * 4 + wv) * 16;   // 16 rows per wave

  bf16x8 ha[4];
#pragma unroll
  for (int ks = 0; ks < 4; ++ks)
    ha[ks] = *(const bf16x8*)(hsb + (long)(r0 + l15) * 128 + ks * 32 + l4 * 8);

  float cntr[4];
#pragma unroll
  for (int r = 0; r < 4; ++r) {
    int row = r0 + l4 * 4 + r;
    if (row > NT - 1) row = NT - 1;
    cntr[r] = (float)(base[row + 1] - base[row]);
  }

  float xv[8][4];
#pragma unroll
  for (int nt = 0; nt < 8; ++nt) {
    bf16x8 bfr2[4];
#pragma unroll
    for (int ks = 0; ks < 4; ++ks)
      bfr2[ks] = *(const bf16x8*)&lw2[swz(nt * 16 + l15, ks * 32 + l4 * 8)];
    float b2v = b2[nt * 16 + l15];
    f32x4 acc = (f32x4){0.f, 0.f, 0.f, 0.f};
#pragma unroll
    for (int ks = 0; ks < 4; ++ks)
      acc = __builtin_amdgcn_mfma_f32_16x16x32_bf16(ha[ks], bfr2[ks], acc, 0, 0, 0);
#pragma unroll
    for (int r = 0; r < 4; ++r) {
      int row = r0 + l4 * 4 + r;
      long o = (long)((row < NT) ? row : NT - 1) * 128 + nt * 16 + l15;
      xv[nt][r] = H[o] + acc[r] + cntr[r] * b2v;
    }
  }

  float mu[4], rs[4];
#pragma unroll
  for (int r = 0; r < 4; ++r) {
    float s = 0.f;
#pragma unroll
    for (int nt = 0; nt < 8; ++nt) s += xv[nt][r];
    s += __shfl_xor(s, 1); s += __shfl_xor(s, 2);
    s += __shfl_xor(s, 4); s += __shfl_xor(s, 8);
    mu[r] = s * (1.0f / 128.0f);
    float q = 0.f;
#pragma unroll
    for (int nt = 0; nt < 8; ++nt) {
      float d = xv[nt][r] - mu[r];
      q += d * d;
    }
    q += __shfl_xor(q, 1); q += __shfl_xor(q, 2);
    q += __shfl_xor(q, 4); q += __shfl_xor(q, 8);
    rs[r] = rsqrtf(q * (1.0f / 128.0f) + 1e-5f);
  }

#pragma unroll
  for (int nt = 0; nt < 8; ++nt) {
    int col = nt * 16 + l15;
    float g = gamma[col], bb = beta[col];
#pragma unroll
    for (int r = 0; r < 4; ++r) {
      int row = r0 + l4 * 4 + r;
      if (row < NT)
        out[(long)row * 128 + col] = (xv[nt][r] - mu[r]) * rs[r] * g + bb;
    }
  }
}

// ---------------- fallback (ws too small): unsorted + far atomics ----------------

template <int BF16H>
__launch_bounds__(256, 1)
__global__ void msg_atomic(const float* __restrict__ H,
                           const u16* __restrict__ Hb,
                           const int* __restrict__ ei,
                           const float* __restrict__ ea,
                           const float* __restrict__ W1,
                           const float* __restrict__ b1,
                           const float* __restrict__ b2,
                           const u16* __restrict__ wsw,
                           float* __restrict__ out) {
  __shared__ __align__(16) u16 lw1[16384];
  __shared__ __align__(16) u16 lw2[16384];
  __shared__ __align__(16) u16 lh[4 * 2048];
  __shared__ __align__(16) float lep[5][128];

  const int tid = threadIdx.x;
  {
    const int4* g = (const int4*)wsw;
    int4* d1 = (int4*)lw1;
    int4* d2 = (int4*)lw2;
#pragma unroll
    for (int i = 0; i < 8; ++i) {
      int c = tid + i * 256;
      d1[c] = g[c];
      d2[c] = g[2048 + c];
    }
  }
  if (tid < 128) {
    lep[0][tid] = b1[tid];
    lep[1][tid] = W1[128 * 128 + tid];
    lep[2][tid] = W1[129 * 128 + tid];
    lep[3][tid] = W1[130 * 128 + tid];
    lep[4][tid] = b2[tid];
  }
  __syncthreads();

  const int wv = tid >> 6, lane = tid & 63;
  const int l15 = lane & 15, l4 = lane >> 4;
  u16* lhw = lh + wv * 2048;
  const int gwid = blockIdx.x * 4 + wv;

  for (int g = gwid; g < NEDGE / 16; g += 4096) {
    const int eb = g * 16;
    int src = ei[eb + l15];
    float ea0 = ea[(eb + l15) * 3 + 0], ea1 = ea[(eb + l15) * 3 + 1], ea2 = ea[(eb + l15) * 3 + 2];

    bf16x8 bfr[4];
    if (BF16H) {
      const u16* hr = Hb + (long)src * 128;
#pragma unroll
      for (int ks = 0; ks < 4; ++ks)
        bfr[ks] = *(const bf16x8*)(hr + ks * 32 + l4 * 8);
    } else {
      const float* hr = H + (long)src * 128;
#pragma unroll
      for (int ks = 0; ks < 4; ++ks) {
        float4 a = *(const float4*)(hr + ks * 32 + l4 * 8);
        float4 c = *(const float4*)(hr + ks * 32 + l4 * 8 + 4);
        int4 pk;
        pk.x = f2bf(a.x) | ((int)f2bf(a.y) << 16);
        pk.y = f2bf(a.z) | ((int)f2bf(a.w) << 16);
        pk.z = f2bf(c.x) | ((int)f2bf(c.y) << 16);
        pk.w = f2bf(c.z) | ((int)f2bf(c.w) << 16);
        bfr[ks] = *(bf16x8*)&pk;
      }
    }

#pragma unroll
    for (int nt = 0; nt < 8; ++nt) {
      bf16x8 afr[4];
#pragma unroll
      for (int ks = 0; ks < 4; ++ks)
        afr[ks] = *(const bf16x8*)&lw1[swz(nt * 16 + l15, ks * 32 + l4 * 8)];
      f32x4 acc = (f32x4){0.f, 0.f, 0.f, 0.f};
#pragma unroll
      for (int ks = 0; ks < 4; ++ks)
        acc = __builtin_amdgcn_mfma_f32_16x16x32_bf16(afr[ks], bfr[ks], acc, 0, 0, 0);
      f32x4 b1v = *(const f32x4*)&lep[0][nt * 16 + l4 * 4];
      f32x4 w0v = *(const f32x4*)&lep[1][nt * 16 + l4 * 4];
      f32x4 w1v = *(const f32x4*)&lep[2][nt * 16 + l4 * 4];
      f32x4 w2v = *(const f32x4*)&lep[3][nt * 16 + l4 * 4];
      float hv[4];
#pragma unroll
      for (int r = 0; r < 4; ++r) {
        float v = acc[r] + b1v[r] + ea0 * w0v[r] + ea1 * w1v[r] + ea2 * w2v[r];
        hv[r] = gelu(v);
      }
      int2 hp;
      hp.x = f2bf(hv[0]) | ((int)f2bf(hv[1]) << 16);
      hp.y = f2bf(hv[2]) | ((int)f2bf(hv[3]) << 16);
      *(int2*)&lhw[swz(l15, nt * 16 + l4 * 4)] = hp;
    }

    asm volatile("" ::: "memory");

    bf16x8 ha[4];
#pragma unroll
    for (int ks = 0; ks < 4; ++ks)
      ha[ks] = *(const bf16x8*)&lhw[swz(l15, ks * 32 + l4 * 8)];
    int drow[4];
#pragma unroll
    for (int r = 0; r < 4; ++r) drow[r] = ei[NEDGE + eb + l4 * 4 + r];

#pragma unroll
    for (int nt = 0; nt < 8; ++nt) {
      bf16x8 bfr2[4];
#pragma unroll
      for (int ks = 0; ks < 4; ++ks)
        bfr2[ks] = *(const bf16x8*)&lw2[swz(nt * 16 + l15, ks * 32 + l4 * 8)];
      float b2v = lep[4][nt * 16 + l15];
      f32x4 acc = (f32x4){0.f, 0.f, 0.f, 0.f};
#pragma unroll
      for (int ks = 0; ks < 4; ++ks)
        acc = __builtin_amdgcn_mfma_f32_16x16x32_bf16(ha[ks], bfr2[ks], acc, 0, 0, 0);
#pragma unroll
      for (int r = 0; r < 4; ++r)
        atomAddF32(out + (long)drow[r] * 128 + nt * 16 + l15, acc[r] + b2v);
    }
  }
}

__global__ void ln_rows(float* __restrict__ out, const float* __restrict__ gamma,
                        const float* __restrict__ beta) {
  int wave = threadIdx.x >> 6, lane = threadIdx.x & 63;
  int row = blockIdx.x * 4 + wave;
  float2 v = *(const float2*)(out + (long)row * 128 + lane * 2);
  float s = v.x + v.y;
#pragma unroll
  for (int off = 32; off; off >>= 1) s += __shfl_xor(s, off);
  float mu = s * (1.0f / 128.0f);
  float dx = v.x - mu, dy = v.y - mu;
  float q = dx * dx + dy * dy;
#pragma unroll
  for (int off = 32; off; off >>= 1) q += __shfl_xor(q, off);
  float rs = rsqrtf(q * (1.0f / 128.0f) + 1e-5f);
  float2 g = *(const float2*)(gamma + lane * 2);
  float2 b = *(const float2*)(beta + lane * 2);
  float2 o;
  o.x = dx * rs * g.x + b.x;
  o.y = dy * rs * g.y + b.y;
  *(float2*)(out + (long)row * 128 + lane * 2) = o;
}

extern "C" void kernel_launch(void* const* d_in, const int* in_sizes, int n_in,
                              void* d_out, int out_size, void* d_ws, size_t ws_size,
                              hipStream_t stream) {
  const float* H   = (const float*)d_in[0];
  const int* ei    = (const int*)d_in[1];
  const float* ea  = (const float*)d_in[2];
  const float* W1  = (const float*)d_in[3];
  const float* b1  = (const float*)d_in[4];
  const float* W2  = (const float*)d_in[5];
  const float* b2  = (const float*)d_in[6];
  const float* gam = (const float*)d_in[7];
  const float* bet = (const float*)d_in[8];
  float* out = (float*)d_out;

  char* ws = (char*)d_ws;
  u16* wsw   = (u16*)ws;                          //     65,536 B @ 0
  u16* wx    = (u16*)(ws + 65536);                //      2,048 B
  u16* Hb    = (u16*)(ws + 67584);                // 12,800,256 B (50001 rows)
  u32* cnt   = (u32*)(ws + 12867840);             //    200,704 B
  u32* base  = (u32*)(ws + 13068544);             //    200,016 B
  u32* pos   = (u32*)(ws + 13268560);             //    200,000 B
  u32* btot  = (u32*)(ws + 13468560);             //        256 B
  uint2* rec = (uint2*)(ws + 13468832);           // 12,800,000 B (8B records)
  u16* hsb   = (u16*)(ws + 26268832);             // 12,812,288 B (50048 rows)
  const size_t NEED_FULL = 39081120;
  const size_t NEED_HB = 12867840;

  if (ws_size >= NEED_FULL) {
    hipMemsetAsync(cnt, 0, NBIN * sizeof(u32), stream);
    prep_all<<<3258, 256, 0, stream>>>(H, Hb, W1, W2, wsw, b1, wx);
    hist_g<<<6250, 256, 0, stream>>>(ei, cnt);
    scan_blk<<<49, 1024, 0, stream>>>(cnt, btot);
    fin_base<<<196, 256, 0, stream>>>(cnt, btot, base, pos);
    scatter_g<<<6250, 256, 0, stream>>>(ei, ea, pos, rec);
    msg_agg<<<GRID, 512, 0, stream>>>(Hb, wsw, wx, base, rec, hsb);
    gemm_ln<<<782, 256, 0, stream>>>(hsb, H, b2, wsw, base, gam, bet, out);
  } else if (ws_size >= NEED_HB) {
    prep_all<<<3258, 256, 0, stream>>>(H, Hb, W1, W2, wsw, b1, wx);
    copy_h<<<6250, 256, 0, stream>>>((const float4*)H, (float4*)out);
    msg_atomic<1><<<1024, 256, 0, stream>>>(H, Hb, ei, ea, W1, b1, b2, wsw, out);
    ln_rows<<<12500, 256, 0, stream>>>(out, gam, bet);
  } else {
    copy_h<<<6250, 256, 0, stream>>>((const float4*)H, (float4*)out);
    msg_atomic<0><<<1024, 256, 0, stream>>>(H, Hb, ei, ea, W1, b1, b2, wsw, out);
    ln_rows<<<12500, 256, 0, stream>>>(out, gam, bet);
  }
}

// Round 13
// 370.641 us; speedup vs baseline: 1.4466x; 1.4466x over previous
//
#include <hip/hip_runtime.h>
#include <hip/hip_bf16.h>

typedef unsigned short u16;
typedef unsigned int u32;
typedef __attribute__((ext_vector_type(8))) __bf16 bf16x8;
typedef __attribute__((ext_vector_type(4))) float f32x4;

#define NT 50000
#define NEDGE 1600000
#define GRID 512
#define NWV 8
#define TOTW 4096           // waves; wrange[] gives each an edge-balanced bucket range
#define NBIN 50176          // padded bins (49*1024)

__device__ __forceinline__ u16 f2bf(float f) {
  unsigned x = __float_as_uint(f);
  x += 0x7fffu + ((x >> 16) & 1u);
  return (u16)(x >> 16);
}

// element index into a [R][128] bf16 tile, 16B-chunk XOR swizzle
__device__ __forceinline__ int swz(int row, int col) {
  return (row << 7) + (col ^ ((row & 7) << 3));
}

// tanh-form GELU (r8 form; gelu(0)==0 exactly — masking relies on this)
__device__ __forceinline__ float gelu(float v) {
  float t = v * (0.797884561f + 0.0356774081f * v * v);
  return v * __builtin_amdgcn_rcpf(1.0f + __expf(-2.0f * t));
}

__device__ __forceinline__ void atomAddF32(float* p, float v) {
#if defined(__has_builtin)
#if __has_builtin(__builtin_amdgcn_global_atomic_fadd_f32)
  __builtin_amdgcn_global_atomic_fadd_f32((__attribute__((address_space(1))) float*)p, v);
  return;
#endif
#endif
  atomicAdd(p, v);
}

// ---------------- merged prep + histogram (cnt zeroed by hipMemsetAsync) ----------------

__global__ void prep_hist(const float* __restrict__ H, u16* __restrict__ Hb,
                          const float* __restrict__ W1, const float* __restrict__ W2,
                          u16* __restrict__ wsw, const float* __restrict__ b1,
                          u16* __restrict__ wx, const int* __restrict__ ei,
                          u32* __restrict__ cnt) {
  int bid = blockIdx.x, tid = threadIdx.x;
  if (bid < 3125) {                    // H f32 -> bf16, 8 elems/thread
    int t = bid * 256 + tid;
    const float4* s = (const float4*)H + (long)t * 2;
    float4 a = s[0], c = s[1];
    int4 pk;
    pk.x = f2bf(a.x) | ((int)f2bf(a.y) << 16);
    pk.y = f2bf(a.z) | ((int)f2bf(a.w) << 16);
    pk.z = f2bf(c.x) | ((int)f2bf(c.y) << 16);
    pk.w = f2bf(c.z) | ((int)f2bf(c.w) << 16);
    ((int4*)Hb)[t] = pk;
  } else if (bid < 3253) {             // W1^T / W2^T bf16, pre-swizzled
    int t = (bid - 3125) * 256 + tid;  // 0..32767
    int m = t >> 14;
    int p = t & 16383;
    int row = p >> 7;
    int colq = p & 127;
    int k = colq ^ ((row & 7) << 3);
    const float* W = m ? W2 : W1;
    wsw[t] = f2bf(W[k * 128 + row]);
  } else if (bid < 3257) {             // K-ext rows: [W1[128..130][n], b1[n], 0,0,0,0]
    int t = (bid - 3253) * 256 + tid;  // 0..1023
    int row = t >> 3, j = t & 7;
    float v = 0.f;
    if (j < 3) v = W1[(128 + j) * 128 + row];
    else if (j == 3) v = b1[row];
    wx[t] = f2bf(v);
  } else if (bid < 3258) {             // zero row NT of Hb (mask target)
    if (tid < 16) ((int4*)(Hb + (long)NT * 128))[tid] = make_int4(0, 0, 0, 0);
  } else {                             // histogram (6250 blocks)
    int e = (bid - 3258) * 256 + tid;
    atomicAdd(&cnt[ei[NEDGE + e]], 1u);
  }
}

__global__ void copy_h(const float4* __restrict__ H, float4* __restrict__ out) {
  int t = blockIdx.x * 256 + threadIdx.x;
  out[t] = H[t];
}

// ---------------- dst bucket sort (bucket == dst row) ----------------

__global__ void hist_g(const int* __restrict__ ei, u32* __restrict__ cnt) {
  int e = blockIdx.x * 256 + threadIdx.x;   // fallback path only
  atomicAdd(&cnt[ei[NEDGE + e]], 1u);
}

__global__ void scan_blk(u32* __restrict__ cnt, u32* __restrict__ btot) {  // <<<49,1024>>>
  __shared__ u32 ls[1024];
  int tid = threadIdx.x;
  int bin = blockIdx.x * 1024 + tid;
  u32 c = cnt[bin];
  ls[tid] = c;
  __syncthreads();
  for (int o = 1; o < 1024; o <<= 1) {
    u32 t = (tid >= o) ? ls[tid - o] : 0u;
    __syncthreads();
    ls[tid] += t;
    __syncthreads();
  }
  cnt[bin] = ls[tid] - c;          // block-local exclusive
  if (tid == 1023) btot[blockIdx.x] = ls[1023];
}

// fin_base: fused btot scan + base/pos fill + wrange (wave->start-bucket) fill.
// wrange pre-memset to 0xFF; unset entries clamp to NT in msg_agg.
__global__ void fin_base(const u32* __restrict__ cnt, const u32* __restrict__ btot,
                         u32* __restrict__ base, u32* __restrict__ pos,
                         u32* __restrict__ wrange) {
  __shared__ u32 bpre[49];
  int tid = threadIdx.x;
  if (tid == 0) {
    u32 run = 0;
    for (int i = 0; i < 49; ++i) { u32 t = btot[i]; bpre[i] = run; run += t; }
  }
  __syncthreads();
  int bin = blockIdx.x * 256 + tid;   // 196*256 = 50176
  if (bin < NT) {
    u32 v = cnt[bin] + bpre[bin >> 10];
    base[bin] = v;
    pos[bin] = v;
    // waves w with floor(w*E/TOTW) in (pv, v] start at this bucket
    long pv = (bin == 0) ? -1L : (long)(cnt[bin - 1] + bpre[(bin - 1) >> 10]);
    long wlo = ((pv + 1) * TOTW + NEDGE - 1) / NEDGE;
    long whi = (((long)v + 1) * TOTW - 1) / NEDGE;
    for (long w = wlo; w <= whi && w < TOTW; ++w) wrange[w] = (u32)bin;
  }
  if (bin == NT) base[NT] = NEDGE;
}

// 8B records: {src | ea0bf<<16, ea1bf | ea2bf<<16}
__global__ void scatter_g(const int* __restrict__ ei, const float* __restrict__ ea,
                          u32* __restrict__ pos, uint2* __restrict__ rec) {
  int e = blockIdx.x * 256 + threadIdx.x;   // 6250 blocks
  int d = ei[NEDGE + e];
  int s = ei[e];
  float e0 = ea[e * 3 + 0], e1 = ea[e * 3 + 1], e2 = ea[e * 3 + 2];
  u32 p = atomicAdd(&pos[d], 1u);
  rec[p] = make_uint2((u32)s | ((u32)f2bf(e0) << 16),
                      (u32)f2bf(e1) | ((u32)f2bf(e2) << 16));
}

// ---------------- aggregated message kernel (r8 body, wrange lookup) ----------------
// D[e][n]: mfma(Hj-rows, W1t-rows); e in (l4,r), n in l15.

__launch_bounds__(512, 2)
__global__ void msg_agg(const u16* __restrict__ Hb,
                        const u16* __restrict__ wsw,
                        const u16* __restrict__ wx,
                        const u32* __restrict__ base,
                        const uint2* __restrict__ rec,
                        const u32* __restrict__ wrange,
                        u16* __restrict__ hsb) {
  __shared__ __align__(16) u16 lw1[16384];        // 32 KB, swizzled W1^T
  __shared__ __align__(16) u16 lw1x[128 * 8];     //  2 KB, K-ext rows

  const int tid = threadIdx.x;
  {
    const int4* g = (const int4*)wsw;
    int4* d1 = (int4*)lw1;
#pragma unroll
    for (int i = 0; i < 4; ++i) { int c = tid + i * 512; d1[c] = g[c]; }
  }
  if (tid < 128) ((int4*)lw1x)[tid] = ((const int4*)wx)[tid];
  __syncthreads();   // only barrier

  const int wv = tid >> 6, lane = tid & 63;
  const int l15 = lane & 15, l4 = lane >> 4;
  const int gid = blockIdx.x * NWV + wv;

  u32 w0 = wrange[gid];
  u32 w1 = wrange[gid + 1];
  const int d0 = (w0 > (u32)NT) ? NT : (int)w0;
  const int d1i = (w1 > (u32)NT) ? NT : (int)w1;

  for (int b = d0; b < d1i; ++b) {
    const int start = (int)base[b];
    const int cnt = (int)base[b + 1] - start;

    float racc[8][4];
#pragma unroll
    for (int nt = 0; nt < 8; ++nt)
#pragma unroll
      for (int r = 0; r < 4; ++r) racc[nt][r] = 0.f;

    const int ntile = (cnt + 15) >> 4;
    uint2 r2c = make_uint2(0, 0);
    if (ntile > 0) {
      int i0 = (l15 < cnt) ? l15 : cnt - 1;
      r2c = rec[start + i0];
    }

    for (int t = 0; t < ntile; ++t) {
      // prefetch next tile's rec
      int inx = (t + 1) * 16 + l15;
      if (inx >= cnt) inx = cnt - 1;
      uint2 r2n = rec[start + inx];

      const bool valid = (t * 16 + l15) < cnt;
      // invalid edge -> zero row of Hb and zero K-ext => column contributes exactly 0
      int src = valid ? (int)(r2c.x & 0xFFFFu) : NT;
      u32 x0 = 0u, x1 = 0u;
      if (l4 == 0 && valid) {
        x0 = (r2c.x >> 16) | (r2c.y << 16);       // ea0 | ea1
        x1 = (r2c.y >> 16) | 0x3F800000u;         // ea2 | bf16(1.0)
      }
      int4 xbi = make_int4((int)x0, (int)x1, 0, 0);
      bf16x8 bfrx = *(bf16x8*)&xbi;

      bf16x8 bfc[4];
      {
        const u16* hr = Hb + (long)src * 128;
#pragma unroll
        for (int ks = 0; ks < 4; ++ks)
          bfc[ks] = *(const bf16x8*)(hr + ks * 32 + l4 * 8);
      }

#pragma unroll
      for (int nt = 0; nt < 8; ++nt) {
        bf16x8 afr[4];
#pragma unroll
        for (int ks = 0; ks < 4; ++ks)
          afr[ks] = *(const bf16x8*)&lw1[swz(nt * 16 + l15, ks * 32 + l4 * 8)];
        bf16x8 afrx = *(const bf16x8*)&lw1x[(nt * 16 + l15) * 8];
        f32x4 acc = (f32x4){0.f, 0.f, 0.f, 0.f};
#pragma unroll
        for (int ks = 0; ks < 4; ++ks)
          acc = __builtin_amdgcn_mfma_f32_16x16x32_bf16(bfc[ks], afr[ks], acc, 0, 0, 0);
        acc = __builtin_amdgcn_mfma_f32_16x16x32_bf16(bfrx, afrx, acc, 0, 0, 0);
#pragma unroll
        for (int r = 0; r < 4; ++r)
          racc[nt][r] += gelu(acc[r]);            // invalid cols are exactly 0
      }
      r2c = r2n;
    }

    // reduce over e: r in-register, l4 via 2 shfl_xor
    float sv[8];
#pragma unroll
    for (int nt = 0; nt < 8; ++nt) {
      float s = racc[nt][0] + racc[nt][1] + racc[nt][2] + racc[nt][3];
      s += __shfl_xor(s, 16);
      s += __shfl_xor(s, 32);
      sv[nt] = s;
    }
    float sa = (l4 == 0) ? sv[0] : (l4 == 1) ? sv[1] : (l4 == 2) ? sv[2] : sv[3];
    float sb = (l4 == 0) ? sv[4] : (l4 == 1) ? sv[5] : (l4 == 2) ? sv[6] : sv[7];
    u16* hrow = hsb + (long)b * 128;
    hrow[l4 * 16 + l15] = f2bf(sa);               // coalesced 128B store
    hrow[64 + l4 * 16 + l15] = f2bf(sb);          // coalesced 128B store
  }
}

// ---------------- fused layer-2 GEMM + residual + LayerNorm ----------------

__launch_bounds__(256)
__global__ void gemm_ln(const u16* __restrict__ hsb,
                        const float* __restrict__ H,
                        const float* __restrict__ b2,
                        const u16* __restrict__ wsw,
                        const u32* __restrict__ base,
                        const float* __restrict__ gamma,
                        const float* __restrict__ beta,
                        float* __restrict__ out) {
  __shared__ __align__(16) u16 lw2[16384];   // swizzled W2^T
  const int tid = threadIdx.x;
  {
    const int4* g = (const int4*)wsw + 2048;   // W2 half
    int4* d2 = (int4*)lw2;
#pragma unroll
    for (int i = 0; i < 8; ++i) { int c = tid + i * 256; d2[c] = g[c]; }
  }
  __syncthreads();

  const int wv = tid >> 6, lane = tid & 63;
  const int l15 = lane & 15, l4 = lane >> 4;
  const int r0 = (blockIdx.x * 4 + wv) * 16;   // 16 rows per wave

  bf16x8 ha[4];
#pragma unroll
  for (int ks = 0; ks < 4; ++ks)
    ha[ks] = *(const bf16x8*)(hsb + (long)(r0 + l15) * 128 + ks * 32 + l4 * 8);

  float cntr[4];
#pragma unroll
  for (int r = 0; r < 4; ++r) {
    int row = r0 + l4 * 4 + r;
    if (row > NT - 1) row = NT - 1;
    cntr[r] = (float)(base[row + 1] - base[row]);
  }

  float xv[8][4];
#pragma unroll
  for (int nt = 0; nt < 8; ++nt) {
    bf16x8 bfr2[4];
#pragma unroll
    for (int ks = 0; ks < 4; ++ks)
      bfr2[ks] = *(const bf16x8*)&lw2[swz(nt * 16 + l15, ks * 32 + l4 * 8)];
    float b2v = b2[nt * 16 + l15];
    f32x4 acc = (f32x4){0.f, 0.f, 0.f, 0.f};
#pragma unroll
    for (int ks = 0; ks < 4; ++ks)
      acc = __builtin_amdgcn_mfma_f32_16x16x32_bf16(ha[ks], bfr2[ks], acc, 0, 0, 0);
#pragma unroll
    for (int r = 0; r < 4; ++r) {
      int row = r0 + l4 * 4 + r;
      long o = (long)((row < NT) ? row : NT - 1) * 128 + nt * 16 + l15;
      xv[nt][r] = H[o] + acc[r] + cntr[r] * b2v;
    }
  }

  float mu[4], rs[4];
#pragma unroll
  for (int r = 0; r < 4; ++r) {
    float s = 0.f;
#pragma unroll
    for (int nt = 0; nt < 8; ++nt) s += xv[nt][r];
    s += __shfl_xor(s, 1); s += __shfl_xor(s, 2);
    s += __shfl_xor(s, 4); s += __shfl_xor(s, 8);
    mu[r] = s * (1.0f / 128.0f);
    float q = 0.f;
#pragma unroll
    for (int nt = 0; nt < 8; ++nt) {
      float d = xv[nt][r] - mu[r];
      q += d * d;
    }
    q += __shfl_xor(q, 1); q += __shfl_xor(q, 2);
    q += __shfl_xor(q, 4); q += __shfl_xor(q, 8);
    rs[r] = rsqrtf(q * (1.0f / 128.0f) + 1e-5f);
  }

#pragma unroll
  for (int nt = 0; nt < 8; ++nt) {
    int col = nt * 16 + l15;
    float g = gamma[col], bb = beta[col];
#pragma unroll
    for (int r = 0; r < 4; ++r) {
      int row = r0 + l4 * 4 + r;
      if (row < NT)
        out[(long)row * 128 + col] = (xv[nt][r] - mu[r]) * rs[r] * g + bb;
    }
  }
}

// ---------------- fallback (ws too small): unsorted + far atomics ----------------

template <int BF16H>
__launch_bounds__(256, 1)
__global__ void msg_atomic(const float* __restrict__ H,
                           const u16* __restrict__ Hb,
                           const int* __restrict__ ei,
                           const float* __restrict__ ea,
                           const float* __restrict__ W1,
                           const float* __restrict__ b1,
                           const float* __restrict__ b2,
                           const u16* __restrict__ wsw,
                           float* __restrict__ out) {
  __shared__ __align__(16) u16 lw1[16384];
  __shared__ __align__(16) u16 lw2[16384];
  __shared__ __align__(16) u16 lh[4 * 2048];
  __shared__ __align__(16) float lep[5][128];

  const int tid = threadIdx.x;
  {
    const int4* g = (const int4*)wsw;
    int4* d1 = (int4*)lw1;
    int4* d2 = (int4*)lw2;
#pragma unroll
    for (int i = 0; i < 8; ++i) {
      int c = tid + i * 256;
      d1[c] = g[c];
      d2[c] = g[2048 + c];
    }
  }
  if (tid < 128) {
    lep[0][tid] = b1[tid];
    lep[1][tid] = W1[128 * 128 + tid];
    lep[2][tid] = W1[129 * 128 + tid];
    lep[3][tid] = W1[130 * 128 + tid];
    lep[4][tid] = b2[tid];
  }
  __syncthreads();

  const int wv = tid >> 6, lane = tid & 63;
  const int l15 = lane & 15, l4 = lane >> 4;
  u16* lhw = lh + wv * 2048;
  const int gwid = blockIdx.x * 4 + wv;

  for (int g = gwid; g < NEDGE / 16; g += 4096) {
    const int eb = g * 16;
    int src = ei[eb + l15];
    float ea0 = ea[(eb + l15) * 3 + 0], ea1 = ea[(eb + l15) * 3 + 1], ea2 = ea[(eb + l15) * 3 + 2];

    bf16x8 bfr[4];
    if (BF16H) {
      const u16* hr = Hb + (long)src * 128;
#pragma unroll
      for (int ks = 0; ks < 4; ++ks)
        bfr[ks] = *(const bf16x8*)(hr + ks * 32 + l4 * 8);
    } else {
      const float* hr = H + (long)src * 128;
#pragma unroll
      for (int ks = 0; ks < 4; ++ks) {
        float4 a = *(const float4*)(hr + ks * 32 + l4 * 8);
        float4 c = *(const float4*)(hr + ks * 32 + l4 * 8 + 4);
        int4 pk;
        pk.x = f2bf(a.x) | ((int)f2bf(a.y) << 16);
        pk.y = f2bf(a.z) | ((int)f2bf(a.w) << 16);
        pk.z = f2bf(c.x) | ((int)f2bf(c.y) << 16);
        pk.w = f2bf(c.z) | ((int)f2bf(c.w) << 16);
        bfr[ks] = *(bf16x8*)&pk;
      }
    }

#pragma unroll
    for (int nt = 0; nt < 8; ++nt) {
      bf16x8 afr[4];
#pragma unroll
      for (int ks = 0; ks < 4; ++ks)
        afr[ks] = *(const bf16x8*)&lw1[swz(nt * 16 + l15, ks * 32 + l4 * 8)];
      f32x4 acc = (f32x4){0.f, 0.f, 0.f, 0.f};
#pragma unroll
      for (int ks = 0; ks < 4; ++ks)
        acc = __builtin_amdgcn_mfma_f32_16x16x32_bf16(afr[ks], bfr[ks], acc, 0, 0, 0);
      f32x4 b1v = *(const f32x4*)&lep[0][nt * 16 + l4 * 4];
      f32x4 w0v = *(const f32x4*)&lep[1][nt * 16 + l4 * 4];
      f32x4 w1v = *(const f32x4*)&lep[2][nt * 16 + l4 * 4];
      f32x4 w2v = *(const f32x4*)&lep[3][nt * 16 + l4 * 4];
      float hv[4];
#pragma unroll
      for (int r = 0; r < 4; ++r) {
        float v = acc[r] + b1v[r] + ea0 * w0v[r] + ea1 * w1v[r] + ea2 * w2v[r];
        hv[r] = gelu(v);
      }
      int2 hp;
      hp.x = f2bf(hv[0]) | ((int)f2bf(hv[1]) << 16);
      hp.y = f2bf(hv[2]) | ((int)f2bf(hv[3]) << 16);
      *(int2*)&lhw[swz(l15, nt * 16 + l4 * 4)] = hp;
    }

    asm volatile("" ::: "memory");

    bf16x8 ha[4];
#pragma unroll
    for (int ks = 0; ks < 4; ++ks)
      ha[ks] = *(const bf16x8*)&lhw[swz(l15, ks * 32 + l4 * 8)];
    int drow[4];
#pragma unroll
    for (int r = 0; r < 4; ++r) drow[r] = ei[NEDGE + eb + l4 * 4 + r];

#pragma unroll
    for (int nt = 0; nt < 8; ++nt) {
      bf16x8 bfr2[4];
#pragma unroll
      for (int ks = 0; ks < 4; ++ks)
        bfr2[ks] = *(const bf16x8*)&lw2[swz(nt * 16 + l15, ks * 32 + l4 * 8)];
      float b2v = lep[4][nt * 16 + l15];
      f32x4 acc = (f32x4){0.f, 0.f, 0.f, 0.f};
#pragma unroll
      for (int ks = 0; ks < 4; ++ks)
        acc = __builtin_amdgcn_mfma_f32_16x16x32_bf16(ha[ks], bfr2[ks], acc, 0, 0, 0);
#pragma unroll
      for (int r = 0; r < 4; ++r)
        atomAddF32(out + (long)drow[r] * 128 + nt * 16 + l15, acc[r] + b2v);
    }
  }
}

__global__ void ln_rows(float* __restrict__ out, const float* __restrict__ gamma,
                        const float* __restrict__ beta) {
  int wave = threadIdx.x >> 6, lane = threadIdx.x & 63;
  int row = blockIdx.x * 4 + wave;
  float2 v = *(const float2*)(out + (long)row * 128 + lane * 2);
  float s = v.x + v.y;
#pragma unroll
  for (int off = 32; off; off >>= 1) s += __shfl_xor(s, off);
  float mu = s * (1.0f / 128.0f);
  float dx = v.x - mu, dy = v.y - mu;
  float q = dx * dx + dy * dy;
#pragma unroll
  for (int off = 32; off; off >>= 1) q += __shfl_xor(q, off);
  float rs = rsqrtf(q * (1.0f / 128.0f) + 1e-5f);
  float2 g = *(const float2*)(gamma + lane * 2);
  float2 b = *(const float2*)(beta + lane * 2);
  float2 o;
  o.x = dx * rs * g.x + b.x;
  o.y = dy * rs * g.y + b.y;
  *(float2*)(out + (long)row * 128 + lane * 2) = o;
}

extern "C" void kernel_launch(void* const* d_in, const int* in_sizes, int n_in,
                              void* d_out, int out_size, void* d_ws, size_t ws_size,
                              hipStream_t stream) {
  const float* H   = (const float*)d_in[0];
  const int* ei    = (const int*)d_in[1];
  const float* ea  = (const float*)d_in[2];
  const float* W1  = (const float*)d_in[3];
  const float* b1  = (const float*)d_in[4];
  const float* W2  = (const float*)d_in[5];
  const float* b2  = (const float*)d_in[6];
  const float* gam = (const float*)d_in[7];
  const float* bet = (const float*)d_in[8];
  float* out = (float*)d_out;

  char* ws = (char*)d_ws;
  u16* wsw    = (u16*)ws;                         //     65,536 B @ 0
  u16* wx     = (u16*)(ws + 65536);               //      2,048 B
  u16* Hb     = (u16*)(ws + 67584);               // 12,800,256 B (50001 rows)
  u32* cnt    = (u32*)(ws + 12867840);            //    200,704 B
  u32* base   = (u32*)(ws + 13068544);            //    200,016 B
  u32* pos    = (u32*)(ws + 13268560);            //    200,000 B
  u32* btot   = (u32*)(ws + 13468560);            //        256 B
  u32* wrange = (u32*)(ws + 13468816);            //     16,400 B (4097 u32 + pad)
  uint2* rec  = (uint2*)(ws + 13485216);          // 12,800,000 B (8B records)
  u16* hsb    = (u16*)(ws + 26285216);            // 12,812,288 B (50048 rows)
  const size_t NEED_FULL = 39097504;
  const size_t NEED_HB = 12867840;

  if (ws_size >= NEED_FULL) {
    hipMemsetAsync(cnt, 0, NBIN * sizeof(u32), stream);
    hipMemsetAsync(wrange, 0xFF, 4097 * sizeof(u32), stream);
    prep_hist<<<9508, 256, 0, stream>>>(H, Hb, W1, W2, wsw, b1, wx, ei, cnt);
    scan_blk<<<49, 1024, 0, stream>>>(cnt, btot);
    fin_base<<<196, 256, 0, stream>>>(cnt, btot, base, pos, wrange);
    scatter_g<<<6250, 256, 0, stream>>>(ei, ea, pos, rec);
    msg_agg<<<GRID, 512, 0, stream>>>(Hb, wsw, wx, base, rec, wrange, hsb);
    gemm_ln<<<782, 256, 0, stream>>>(hsb, H, b2, wsw, base, gam, bet, out);
  } else if (ws_size >= NEED_HB) {
    hipMemsetAsync(cnt, 0, NBIN * sizeof(u32), stream);
    prep_hist<<<3258, 256, 0, stream>>>(H, Hb, W1, W2, wsw, b1, wx, ei, cnt);
    copy_h<<<6250, 256, 0, stream>>>((const float4*)H, (float4*)out);
    msg_atomic<1><<<1024, 256, 0, stream>>>(H, Hb, ei, ea, W1, b1, b2, wsw, out);
    ln_rows<<<12500, 256, 0, stream>>>(out, gam, bet);
  } else {
    copy_h<<<6250, 256, 0, stream>>>((const float4*)H, (float4*)out);
    msg_atomic<0><<<1024, 256, 0, stream>>>(H, Hb, ei, ea, W1, b1, b2, wsw, out);
    ln_rows<<<12500, 256, 0, stream>>>(out, gam, bet);
  }
}

// Round 14
// 343.742 us; speedup vs baseline: 1.5598x; 1.0783x over previous
//
#include <hip/hip_runtime.h>
#include <hip/hip_bf16.h>

typedef unsigned short u16;
typedef unsigned int u32;
typedef __attribute__((ext_vector_type(8))) __bf16 bf16x8;
typedef __attribute__((ext_vector_type(4))) float f32x4;

#define NT 50000
#define NEDGE 1600000
#define GRID 512
#define NWV 8
#define TOTW 4096           // waves; wrange[] gives each an edge-balanced bucket range
#define NBIN 50176          // padded bins (49*1024)

__device__ __forceinline__ u16 f2bf(float f) {
  unsigned x = __float_as_uint(f);
  x += 0x7fffu + ((x >> 16) & 1u);
  return (u16)(x >> 16);
}

// element index into a [R][128] bf16 tile, 16B-chunk XOR swizzle
__device__ __forceinline__ int swz(int row, int col) {
  return (row << 7) + (col ^ ((row & 7) << 3));
}

// tanh-form GELU via exp2 (r10-validated; gelu(0)==0 exactly — masking relies on this)
__device__ __forceinline__ float gelu(float v) {
  float u = v * v;
  float arg = v * __builtin_fmaf(-0.1029434f, u, -2.3022082f);  // -2*log2e*(c1+c2*u)
  float e = __builtin_amdgcn_exp2f(arg);
  return v * __builtin_amdgcn_rcpf(1.0f + e);
}

__device__ __forceinline__ void atomAddF32(float* p, float v) {
#if defined(__has_builtin)
#if __has_builtin(__builtin_amdgcn_global_atomic_fadd_f32)
  __builtin_amdgcn_global_atomic_fadd_f32((__attribute__((address_space(1))) float*)p, v);
  return;
#endif
#endif
  atomicAdd(p, v);
}

// ---------------- merged prep (no memsets: cnt + wrange zeroed here) ----------------

__global__ void prep_all(const float* __restrict__ H, u16* __restrict__ Hb,
                         const float* __restrict__ W1, const float* __restrict__ W2,
                         u16* __restrict__ wsw, const float* __restrict__ b1,
                         u16* __restrict__ wx, u32* __restrict__ cnt,
                         u32* __restrict__ wrange) {
  int bid = blockIdx.x, tid = threadIdx.x;
  if (bid < 3125) {                    // H f32 -> bf16, 8 elems/thread
    int t = bid * 256 + tid;
    const float4* s = (const float4*)H + (long)t * 2;
    float4 a = s[0], c = s[1];
    int4 pk;
    pk.x = f2bf(a.x) | ((int)f2bf(a.y) << 16);
    pk.y = f2bf(a.z) | ((int)f2bf(a.w) << 16);
    pk.z = f2bf(c.x) | ((int)f2bf(c.y) << 16);
    pk.w = f2bf(c.z) | ((int)f2bf(c.w) << 16);
    ((int4*)Hb)[t] = pk;
  } else if (bid < 3253) {             // W1^T / W2^T bf16, pre-swizzled
    int t = (bid - 3125) * 256 + tid;  // 0..32767
    int m = t >> 14;
    int p = t & 16383;
    int row = p >> 7;
    int colq = p & 127;
    int k = colq ^ ((row & 7) << 3);
    const float* W = m ? W2 : W1;
    wsw[t] = f2bf(W[k * 128 + row]);
  } else if (bid < 3257) {             // K-ext rows: [W1[128..130][n], b1[n], 0,0,0,0]
    int t = (bid - 3253) * 256 + tid;  // 0..1023
    int row = t >> 3, j = t & 7;
    float v = 0.f;
    if (j < 3) v = W1[(128 + j) * 128 + row];
    else if (j == 3) v = b1[row];
    wx[t] = f2bf(v);
  } else if (bid < 3258) {             // zero row NT of Hb (mask target)
    if (tid < 16) ((int4*)(Hb + (long)NT * 128))[tid] = make_int4(0, 0, 0, 0);
  } else if (bid < 3454) {             // zero histogram bins (196 blocks)
    int t = (bid - 3258) * 256 + tid;
    if (t < NBIN) cnt[t] = 0;
  } else {                             // wrange init to 0xFFFFFFFF (17 blocks)
    int t = (bid - 3454) * 256 + tid;
    if (t < TOTW + 1) wrange[t] = 0xFFFFFFFFu;
  }
}

__global__ void copy_h(const float4* __restrict__ H, float4* __restrict__ out) {
  int t = blockIdx.x * 256 + threadIdx.x;
  out[t] = H[t];
}

// ---------------- dst bucket sort (bucket == dst row) ----------------

__global__ void hist_g(const int* __restrict__ ei, u32* __restrict__ cnt) {
  int e = blockIdx.x * 256 + threadIdx.x;   // 6250 blocks
  atomicAdd(&cnt[ei[NEDGE + e]], 1u);
}

__global__ void scan_blk(u32* __restrict__ cnt, u32* __restrict__ btot) {  // <<<49,1024>>>
  __shared__ u32 ls[1024];
  int tid = threadIdx.x;
  int bin = blockIdx.x * 1024 + tid;
  u32 c = cnt[bin];
  ls[tid] = c;
  __syncthreads();
  for (int o = 1; o < 1024; o <<= 1) {
    u32 t = (tid >= o) ? ls[tid - o] : 0u;
    __syncthreads();
    ls[tid] += t;
    __syncthreads();
  }
  cnt[bin] = ls[tid] - c;          // block-local exclusive
  if (tid == 1023) btot[blockIdx.x] = ls[1023];
}

// fin_base: fused btot scan + base/pos fill + wrange (wave->start-bucket) fill.
// wrange pre-initialized to 0xFF; unset entries clamp to NT in msg_agg.
__global__ void fin_base(const u32* __restrict__ cnt, const u32* __restrict__ btot,
                         u32* __restrict__ base, u32* __restrict__ pos,
                         u32* __restrict__ wrange) {
  __shared__ u32 bpre[49];
  int tid = threadIdx.x;
  if (tid == 0) {
    u32 run = 0;
    for (int i = 0; i < 49; ++i) { u32 t = btot[i]; bpre[i] = run; run += t; }
  }
  __syncthreads();
  int bin = blockIdx.x * 256 + tid;   // 196*256 = 50176
  if (bin < NT) {
    u32 v = cnt[bin] + bpre[bin >> 10];
    base[bin] = v;
    pos[bin] = v;
    // waves w with floor(w*E/TOTW) in (pv, v] start at this bucket
    long pv = (bin == 0) ? -1L : (long)(cnt[bin - 1] + bpre[(bin - 1) >> 10]);
    long wlo = ((pv + 1) * TOTW + NEDGE - 1) / NEDGE;
    long whi = (((long)v + 1) * TOTW - 1) / NEDGE;
    for (long w = wlo; w <= whi && w < TOTW; ++w) wrange[w] = (u32)bin;
  }
  if (bin == NT) base[NT] = NEDGE;
}

// 8B records: {src | ea0bf<<16, ea1bf | ea2bf<<16}
__global__ void scatter_g(const int* __restrict__ ei, const float* __restrict__ ea,
                          u32* __restrict__ pos, uint2* __restrict__ rec) {
  int e = blockIdx.x * 256 + threadIdx.x;   // 6250 blocks
  int d = ei[NEDGE + e];
  int s = ei[e];
  float e0 = ea[e * 3 + 0], e1 = ea[e * 3 + 1], e2 = ea[e * 3 + 2];
  u32 p = atomicAdd(&pos[d], 1u);
  rec[p] = make_uint2((u32)s | ((u32)f2bf(e0) << 16),
                      (u32)f2bf(e1) | ((u32)f2bf(e2) << 16));
}

// ---------------- aggregated message kernel (r8 body, wrange lookup) ----------------
// D[e][n]: mfma(Hj-rows, W1t-rows); e in (l4,r), n in l15.

__launch_bounds__(512, 2)
__global__ void msg_agg(const u16* __restrict__ Hb,
                        const u16* __restrict__ wsw,
                        const u16* __restrict__ wx,
                        const u32* __restrict__ base,
                        const uint2* __restrict__ rec,
                        const u32* __restrict__ wrange,
                        u16* __restrict__ hsb) {
  __shared__ __align__(16) u16 lw1[16384];        // 32 KB, swizzled W1^T
  __shared__ __align__(16) u16 lw1x[128 * 8];     //  2 KB, K-ext rows

  const int tid = threadIdx.x;
  {
    const int4* g = (const int4*)wsw;
    int4* d1 = (int4*)lw1;
#pragma unroll
    for (int i = 0; i < 4; ++i) { int c = tid + i * 512; d1[c] = g[c]; }
  }
  if (tid < 128) ((int4*)lw1x)[tid] = ((const int4*)wx)[tid];
  __syncthreads();   // only barrier

  const int wv = tid >> 6, lane = tid & 63;
  const int l15 = lane & 15, l4 = lane >> 4;
  const int gid = blockIdx.x * NWV + wv;

  u32 w0 = wrange[gid];
  u32 w1 = wrange[gid + 1];
  const int d0 = (w0 > (u32)NT) ? NT : (int)w0;
  const int d1i = (w1 > (u32)NT) ? NT : (int)w1;

  for (int b = d0; b < d1i; ++b) {
    const int start = (int)base[b];
    const int cnt = (int)base[b + 1] - start;

    float racc[8][4];
#pragma unroll
    for (int nt = 0; nt < 8; ++nt)
#pragma unroll
      for (int r = 0; r < 4; ++r) racc[nt][r] = 0.f;

    const int ntile = (cnt + 15) >> 4;
    uint2 r2c = make_uint2(0, 0);
    if (ntile > 0) {
      int i0 = (l15 < cnt) ? l15 : cnt - 1;
      r2c = rec[start + i0];
    }

    for (int t = 0; t < ntile; ++t) {
      // prefetch next tile's rec
      int inx = (t + 1) * 16 + l15;
      if (inx >= cnt) inx = cnt - 1;
      uint2 r2n = rec[start + inx];

      const bool valid = (t * 16 + l15) < cnt;
      // invalid edge -> zero row of Hb and zero K-ext => column contributes exactly 0
      int src = valid ? (int)(r2c.x & 0xFFFFu) : NT;
      u32 x0 = 0u, x1 = 0u;
      if (l4 == 0 && valid) {
        x0 = (r2c.x >> 16) | (r2c.y << 16);       // ea0 | ea1
        x1 = (r2c.y >> 16) | 0x3F800000u;         // ea2 | bf16(1.0)
      }
      int4 xbi = make_int4((int)x0, (int)x1, 0, 0);
      bf16x8 bfrx = *(bf16x8*)&xbi;

      bf16x8 bfc[4];
      {
        const u16* hr = Hb + (long)src * 128;
#pragma unroll
        for (int ks = 0; ks < 4; ++ks)
          bfc[ks] = *(const bf16x8*)(hr + ks * 32 + l4 * 8);
      }

#pragma unroll
      for (int nt = 0; nt < 8; ++nt) {
        bf16x8 afr[4];
#pragma unroll
        for (int ks = 0; ks < 4; ++ks)
          afr[ks] = *(const bf16x8*)&lw1[swz(nt * 16 + l15, ks * 32 + l4 * 8)];
        bf16x8 afrx = *(const bf16x8*)&lw1x[(nt * 16 + l15) * 8];
        f32x4 acc = (f32x4){0.f, 0.f, 0.f, 0.f};
#pragma unroll
        for (int ks = 0; ks < 4; ++ks)
          acc = __builtin_amdgcn_mfma_f32_16x16x32_bf16(bfc[ks], afr[ks], acc, 0, 0, 0);
        acc = __builtin_amdgcn_mfma_f32_16x16x32_bf16(bfrx, afrx, acc, 0, 0, 0);
#pragma unroll
        for (int r = 0; r < 4; ++r)
          racc[nt][r] += gelu(acc[r]);            // invalid cols are exactly 0
      }
      r2c = r2n;
    }

    // reduce over e: r in-register, l4 via 2 shfl_xor
    float sv[8];
#pragma unroll
    for (int nt = 0; nt < 8; ++nt) {
      float s = racc[nt][0] + racc[nt][1] + racc[nt][2] + racc[nt][3];
      s += __shfl_xor(s, 16);
      s += __shfl_xor(s, 32);
      sv[nt] = s;
    }
    float sa = (l4 == 0) ? sv[0] : (l4 == 1) ? sv[1] : (l4 == 2) ? sv[2] : sv[3];
    float sb = (l4 == 0) ? sv[4] : (l4 == 1) ? sv[5] : (l4 == 2) ? sv[6] : sv[7];
    u16* hrow = hsb + (long)b * 128;
    hrow[l4 * 16 + l15] = f2bf(sa);               // coalesced 128B store
    hrow[64 + l4 * 16 + l15] = f2bf(sb);          // coalesced 128B store
  }
}

// ---------------- fused layer-2 GEMM + residual + LayerNorm ----------------

__launch_bounds__(256)
__global__ void gemm_ln(const u16* __restrict__ hsb,
                        const float* __restrict__ H,
                        const float* __restrict__ b2,
                        const u16* __restrict__ wsw,
                        const u32* __restrict__ base,
                        const float* __restrict__ gamma,
                        const float* __restrict__ beta,
                        float* __restrict__ out) {
  __shared__ __align__(16) u16 lw2[16384];   // swizzled W2^T
  const int tid = threadIdx.x;
  {
    const int4* g = (const int4*)wsw + 2048;   // W2 half
    int4* d2 = (int4*)lw2;
#pragma unroll
    for (int i = 0; i < 8; ++i) { int c = tid + i * 256; d2[c] = g[c]; }
  }
  __syncthreads();

  const int wv = tid >> 6, lane = tid & 63;
  const int l15 = lane & 15, l4 = lane >> 4;
  const int r0 = (blockIdx.x * 4 + wv) * 16;   // 16 rows per wave

  bf16x8 ha[4];
#pragma unroll
  for (int ks = 0; ks < 4; ++ks)
    ha[ks] = *(const bf16x8*)(hsb + (long)(r0 + l15) * 128 + ks * 32 + l4 * 8);

  float cntr[4];
#pragma unroll
  for (int r = 0; r < 4; ++r) {
    int row = r0 + l4 * 4 + r;
    if (row > NT - 1) row = NT - 1;
    cntr[r] = (float)(base[row + 1] - base[row]);
  }

  float xv[8][4];
#pragma unroll
  for (int nt = 0; nt < 8; ++nt) {
    bf16x8 bfr2[4];
#pragma unroll
    for (int ks = 0; ks < 4; ++ks)
      bfr2[ks] = *(const bf16x8*)&lw2[swz(nt * 16 + l15, ks * 32 + l4 * 8)];
    float b2v = b2[nt * 16 + l15];
    f32x4 acc = (f32x4){0.f, 0.f, 0.f, 0.f};
#pragma unroll
    for (int ks = 0; ks < 4; ++ks)
      acc = __builtin_amdgcn_mfma_f32_16x16x32_bf16(ha[ks], bfr2[ks], acc, 0, 0, 0);
#pragma unroll
    for (int r = 0; r < 4; ++r) {
      int row = r0 + l4 * 4 + r;
      long o = (long)((row < NT) ? row : NT - 1) * 128 + nt * 16 + l15;
      xv[nt][r] = H[o] + acc[r] + cntr[r] * b2v;
    }
  }

  float mu[4], rs[4];
#pragma unroll
  for (int r = 0; r < 4; ++r) {
    float s = 0.f;
#pragma unroll
    for (int nt = 0; nt < 8; ++nt) s += xv[nt][r];
    s += __shfl_xor(s, 1); s += __shfl_xor(s, 2);
    s += __shfl_xor(s, 4); s += __shfl_xor(s, 8);
    mu[r] = s * (1.0f / 128.0f);
    float q = 0.f;
#pragma unroll
    for (int nt = 0; nt < 8; ++nt) {
      float d = xv[nt][r] - mu[r];
      q += d * d;
    }
    q += __shfl_xor(q, 1); q += __shfl_xor(q, 2);
    q += __shfl_xor(q, 4); q += __shfl_xor(q, 8);
    rs[r] = rsqrtf(q * (1.0f / 128.0f) + 1e-5f);
  }

#pragma unroll
  for (int nt = 0; nt < 8; ++nt) {
    int col = nt * 16 + l15;
    float g = gamma[col], bb = beta[col];
#pragma unroll
    for (int r = 0; r < 4; ++r) {
      int row = r0 + l4 * 4 + r;
      if (row < NT)
        out[(long)row * 128 + col] = (xv[nt][r] - mu[r]) * rs[r] * g + bb;
    }
  }
}

// ---------------- fallback (ws too small): unsorted + far atomics ----------------

template <int BF16H>
__launch_bounds__(256, 1)
__global__ void msg_atomic(const float* __restrict__ H,
                           const u16* __restrict__ Hb,
                           const int* __restrict__ ei,
                           const float* __restrict__ ea,
                           const float* __restrict__ W1,
                           const float* __restrict__ b1,
                           const float* __restrict__ b2,
                           const u16* __restrict__ wsw,
                           float* __restrict__ out) {
  __shared__ __align__(16) u16 lw1[16384];
  __shared__ __align__(16) u16 lw2[16384];
  __shared__ __align__(16) u16 lh[4 * 2048];
  __shared__ __align__(16) float lep[5][128];

  const int tid = threadIdx.x;
  {
    const int4* g = (const int4*)wsw;
    int4* d1 = (int4*)lw1;
    int4* d2 = (int4*)lw2;
#pragma unroll
    for (int i = 0; i < 8; ++i) {
      int c = tid + i * 256;
      d1[c] = g[c];
      d2[c] = g[2048 + c];
    }
  }
  if (tid < 128) {
    lep[0][tid] = b1[tid];
    lep[1][tid] = W1[128 * 128 + tid];
    lep[2][tid] = W1[129 * 128 + tid];
    lep[3][tid] = W1[130 * 128 + tid];
    lep[4][tid] = b2[tid];
  }
  __syncthreads();

  const int wv = tid >> 6, lane = tid & 63;
  const int l15 = lane & 15, l4 = lane >> 4;
  u16* lhw = lh + wv * 2048;
  const int gwid = blockIdx.x * 4 + wv;

  for (int g = gwid; g < NEDGE / 16; g += 4096) {
    const int eb = g * 16;
    int src = ei[eb + l15];
    float ea0 = ea[(eb + l15) * 3 + 0], ea1 = ea[(eb + l15) * 3 + 1], ea2 = ea[(eb + l15) * 3 + 2];

    bf16x8 bfr[4];
    if (BF16H) {
      const u16* hr = Hb + (long)src * 128;
#pragma unroll
      for (int ks = 0; ks < 4; ++ks)
        bfr[ks] = *(const bf16x8*)(hr + ks * 32 + l4 * 8);
    } else {
      const float* hr = H + (long)src * 128;
#pragma unroll
      for (int ks = 0; ks < 4; ++ks) {
        float4 a = *(const float4*)(hr + ks * 32 + l4 * 8);
        float4 c = *(const float4*)(hr + ks * 32 + l4 * 8 + 4);
        int4 pk;
        pk.x = f2bf(a.x) | ((int)f2bf(a.y) << 16);
        pk.y = f2bf(a.z) | ((int)f2bf(a.w) << 16);
        pk.z = f2bf(c.x) | ((int)f2bf(c.y) << 16);
        pk.w = f2bf(c.z) | ((int)f2bf(c.w) << 16);
        bfr[ks] = *(bf16x8*)&pk;
      }
    }

#pragma unroll
    for (int nt = 0; nt < 8; ++nt) {
      bf16x8 afr[4];
#pragma unroll
      for (int ks = 0; ks < 4; ++ks)
        afr[ks] = *(const bf16x8*)&lw1[swz(nt * 16 + l15, ks * 32 + l4 * 8)];
      f32x4 acc = (f32x4){0.f, 0.f, 0.f, 0.f};
#pragma unroll
      for (int ks = 0; ks < 4; ++ks)
        acc = __builtin_amdgcn_mfma_f32_16x16x32_bf16(afr[ks], bfr[ks], acc, 0, 0, 0);
      f32x4 b1v = *(const f32x4*)&lep[0][nt * 16 + l4 * 4];
      f32x4 w0v = *(const f32x4*)&lep[1][nt * 16 + l4 * 4];
      f32x4 w1v = *(const f32x4*)&lep[2][nt * 16 + l4 * 4];
      f32x4 w2v = *(const f32x4*)&lep[3][nt * 16 + l4 * 4];
      float hv[4];
#pragma unroll
      for (int r = 0; r < 4; ++r) {
        float v = acc[r] + b1v[r] + ea0 * w0v[r] + ea1 * w1v[r] + ea2 * w2v[r];
        hv[r] = gelu(v);
      }
      int2 hp;
      hp.x = f2bf(hv[0]) | ((int)f2bf(hv[1]) << 16);
      hp.y = f2bf(hv[2]) | ((int)f2bf(hv[3]) << 16);
      *(int2*)&lhw[swz(l15, nt * 16 + l4 * 4)] = hp;
    }

    asm volatile("" ::: "memory");

    bf16x8 ha[4];
#pragma unroll
    for (int ks = 0; ks < 4; ++ks)
      ha[ks] = *(const bf16x8*)&lhw[swz(l15, ks * 32 + l4 * 8)];
    int drow[4];
#pragma unroll
    for (int r = 0; r < 4; ++r) drow[r] = ei[NEDGE + eb + l4 * 4 + r];

#pragma unroll
    for (int nt = 0; nt < 8; ++nt) {
      bf16x8 bfr2[4];
#pragma unroll
      for (int ks = 0; ks < 4; ++ks)
        bfr2[ks] = *(const bf16x8*)&lw2[swz(nt * 16 + l15, ks * 32 + l4 * 8)];
      float b2v = lep[4][nt * 16 + l15];
      f32x4 acc = (f32x4){0.f, 0.f, 0.f, 0.f};
#pragma unroll
      for (int ks = 0; ks < 4; ++ks)
        acc = __builtin_amdgcn_mfma_f32_16x16x32_bf16(ha[ks], bfr2[ks], acc, 0, 0, 0);
#pragma unroll
      for (int r = 0; r < 4; ++r)
        atomAddF32(out + (long)drow[r] * 128 + nt * 16 + l15, acc[r] + b2v);
    }
  }
}

__global__ void ln_rows(float* __restrict__ out, const float* __restrict__ gamma,
                        const float* __restrict__ beta) {
  int wave = threadIdx.x >> 6, lane = threadIdx.x & 63;
  int row = blockIdx.x * 4 + wave;
  float2 v = *(const float2*)(out + (long)row * 128 + lane * 2);
  float s = v.x + v.y;
#pragma unroll
  for (int off = 32; off; off >>= 1) s += __shfl_xor(s, off);
  float mu = s * (1.0f / 128.0f);
  float dx = v.x - mu, dy = v.y - mu;
  float q = dx * dx + dy * dy;
#pragma unroll
  for (int off = 32; off; off >>= 1) q += __shfl_xor(q, off);
  float rs = rsqrtf(q * (1.0f / 128.0f) + 1e-5f);
  float2 g = *(const float2*)(gamma + lane * 2);
  float2 b = *(const float2*)(beta + lane * 2);
  float2 o;
  o.x = dx * rs * g.x + b.x;
  o.y = dy * rs * g.y + b.y;
  *(float2*)(out + (long)row * 128 + lane * 2) = o;
}

extern "C" void kernel_launch(void* const* d_in, const int* in_sizes, int n_in,
                              void* d_out, int out_size, void* d_ws, size_t ws_size,
                              hipStream_t stream) {
  const float* H   = (const float*)d_in[0];
  const int* ei    = (const int*)d_in[1];
  const float* ea  = (const float*)d_in[2];
  const float* W1  = (const float*)d_in[3];
  const float* b1  = (const float*)d_in[4];
  const float* W2  = (const float*)d_in[5];
  const float* b2  = (const float*)d_in[6];
  const float* gam = (const float*)d_in[7];
  const float* bet = (const float*)d_in[8];
  float* out = (float*)d_out;

  char* ws = (char*)d_ws;
  u16* wsw    = (u16*)ws;                         //     65,536 B @ 0
  u16* wx     = (u16*)(ws + 65536);               //      2,048 B
  u16* Hb     = (u16*)(ws + 67584);               // 12,800,256 B (50001 rows)
  u32* cnt    = (u32*)(ws + 12867840);            //    200,704 B
  u32* base   = (u32*)(ws + 13068544);            //    200,016 B
  u32* pos    = (u32*)(ws + 13268560);            //    200,000 B
  u32* btot   = (u32*)(ws + 13468560);            //        256 B
  u32* wrange = (u32*)(ws + 13468816);            //     16,400 B (4097 u32 + pad)
  uint2* rec  = (uint2*)(ws + 13485216);          // 12,800,000 B (8B records)
  u16* hsb    = (u16*)(ws + 26285216);            // 12,812,288 B (50048 rows)
  const size_t NEED_FULL = 39097504;
  const size_t NEED_HB = 12867840;

  if (ws_size >= NEED_FULL) {
    prep_all<<<3471, 256, 0, stream>>>(H, Hb, W1, W2, wsw, b1, wx, cnt, wrange);
    hist_g<<<6250, 256, 0, stream>>>(ei, cnt);
    scan_blk<<<49, 1024, 0, stream>>>(cnt, btot);
    fin_base<<<196, 256, 0, stream>>>(cnt, btot, base, pos, wrange);
    scatter_g<<<6250, 256, 0, stream>>>(ei, ea, pos, rec);
    msg_agg<<<GRID, 512, 0, stream>>>(Hb, wsw, wx, base, rec, wrange, hsb);
    gemm_ln<<<782, 256, 0, stream>>>(hsb, H, b2, wsw, base, gam, bet, out);
  } else if (ws_size >= NEED_HB) {
    prep_all<<<3258, 256, 0, stream>>>(H, Hb, W1, W2, wsw, b1, wx, cnt, wrange);
    copy_h<<<6250, 256, 0, stream>>>((const float4*)H, (float4*)out);
    msg_atomic<1><<<1024, 256, 0, stream>>>(H, Hb, ei, ea, W1, b1, b2, wsw, out);
    ln_rows<<<12500, 256, 0, stream>>>(out, gam, bet);
  } else {
    copy_h<<<6250, 256, 0, stream>>>((const float4*)H, (float4*)out);
    msg_atomic<0><<<1024, 256, 0, stream>>>(H, Hb, ei, ea, W1, b1, b2, wsw, out);
    ln_rows<<<12500, 256, 0, stream>>>(out, gam, bet);
  }
}